// Round 4
// baseline (201.085 us; speedup 1.0000x reference)
//
#include <hip/hip_runtime.h>
#include <hip/hip_bf16.h>
#include <stdint.h>

// GroupTorchGRU: B=1024, U=8, I=H=512, fp32 in/out.
// R4: two-kernel design.
//  K1: fp32 -> bf16 conversion of X, H, W_ih, W_hh into d_ws (42 MB).
//  K2: fused GEMM+gates. global_load_lds(16B) direct staging, BK=64,
//      XOR-swizzled LDS (conflict-free writes AND b128 reads),
//      gate-split waves (4 waves gx, 4 waves gh), XCD-aware grid
//      (id%8 = nb so per-XCD L2 weight set = 3MB).
// Fallback: R3 single-kernel path if ws_size too small.

#define B_ 1024
#define U_ 8
#define I_ 512
#define H_ 512
#define KDIM 512

#define NX (B_ * U_ * I_)        // 4194304 elems
#define NW (U_ * 3 * H_ * I_)    // 6291456 elems
#define OFF_X 0
#define OFF_H NX
#define OFF_WIH (2 * NX)
#define OFF_WHH (2 * NX + NW)
#define NTOT (2 * NX + 2 * NW)   // 20971520 elems
#define WS_NEED ((size_t)NTOT * 2)

#define BM 64
#define BN 64
#define BK 64
#define ESTR 68                  // fp32 epilogue row stride (64+4)

typedef __attribute__((ext_vector_type(8))) short short8;   // 8 bf16
typedef __attribute__((ext_vector_type(4))) float floatx4;  // MFMA C/D

__device__ __forceinline__ unsigned int pk2bf(float a, float b) {
    float2 f2; f2.x = a; f2.y = b;
    union { __hip_bfloat162 h; unsigned int u; } cv;
    cv.h = __float22bfloat162_rn(f2);  // v_cvt_pk_bf16_f32
    return cv.u;
}

__device__ __forceinline__ void async16(const void* g, void* l) {
    __builtin_amdgcn_global_load_lds(
        (const __attribute__((address_space(1))) void*)g,
        (__attribute__((address_space(3))) void*)l, 16, 0, 0);
}

// ---------------- K1: fp32 -> bf16 prepass ----------------
__global__ __launch_bounds__(256)
void convert_bf16_kernel(const float* __restrict__ x, const float* __restrict__ h,
                         const float* __restrict__ wih, const float* __restrict__ whh,
                         unsigned short* __restrict__ ws)
{
    const size_t base = ((size_t)blockIdx.x * 256 + threadIdx.x) * 8;
    const float* src; size_t off;
    if (base < (size_t)OFF_H)        { src = x;   off = OFF_X; }
    else if (base < (size_t)OFF_WIH) { src = h;   off = OFF_H; }
    else if (base < (size_t)OFF_WHH) { src = wih; off = OFF_WIH; }
    else                             { src = whh; off = OFF_WHH; }
    const float4 v0 = *(const float4*)(src + (base - off));
    const float4 v1 = *(const float4*)(src + (base - off) + 4);
    uint4 o;
    o.x = pk2bf(v0.x, v0.y);
    o.y = pk2bf(v0.z, v0.w);
    o.z = pk2bf(v1.x, v1.y);
    o.w = pk2bf(v1.z, v1.w);
    *(uint4*)(ws + base) = o;
}

// ---------------- K2: fused bf16 GEMM + GRU gates ----------------
// LDS slab: 64 rows x 64 bf16 (128B rows, 8 x 16B chunks).
// Physical chunk p of row r holds logical chunk p ^ (r&7).
union Smem {
    unsigned short bf[8][64 * 64];   // 8 slabs x 8KB = 64KB
    float ep[3][BM * ESTR];          // 52224B epilogue exchange
};

__global__ __launch_bounds__(512, 4)
void gru_main_kernel(const unsigned short* __restrict__ ws,  // bf16 X|H|Wih|Whh
                     const float* __restrict__ hidden,       // fp32, epilogue
                     const float* __restrict__ b_ih,
                     const float* __restrict__ b_hh,
                     float* __restrict__ out)
{
    const int u  = blockIdx.x >> 3;  // x fastest: id%8 = nb -> XCD-local weights
    const int nb = blockIdx.x & 7;
    const int mb = blockIdx.y;
    const int b0 = mb * BM;
    const int h0 = nb * BN;

    const int tid  = threadIdx.x;
    const int lane = tid & 63;
    const int wave = tid >> 6;        // 0..7
    const int lr   = lane & 15;
    const int q    = lane >> 4;
    const int wm   = wave & 1;
    const int wn   = (wave >> 1) & 1;
    const int g2   = wave >> 2;       // 0: gx waves, 1: gh waves

    __shared__ Smem smem;

    // This wave's staging slab (slab index == wave):
    // 0=X, 1=Hprev, 2..4=W_ih r/z/n, 5..7=W_hh r/z/n
    const unsigned short* gbase; int grstr;
    if (wave == 0)      { gbase = ws + OFF_X + ((size_t)b0 * U_ + u) * I_; grstr = U_ * I_; }
    else if (wave == 1) { gbase = ws + OFF_H + ((size_t)b0 * U_ + u) * H_; grstr = U_ * H_; }
    else if (wave <= 4) { int g = wave - 2; gbase = ws + OFF_WIH + ((size_t)(u * 3 + g) * H_ + h0) * I_; grstr = I_; }
    else                { int g = wave - 5; gbase = ws + OFF_WHH + ((size_t)(u * 3 + g) * H_ + h0) * H_; grstr = H_; }

    const int rsub = lane >> 3;            // 0..7 row-within-8
    const int lch  = (lane & 7) ^ rsub;    // logical 16B chunk this lane fetches

    floatx4 acc[3][2][2];
    #pragma unroll
    for (int g = 0; g < 3; ++g)
        #pragma unroll
        for (int mt = 0; mt < 2; ++mt)
            #pragma unroll
            for (int nt = 0; nt < 2; ++nt)
                acc[g][mt][nt] = (floatx4){0.f, 0.f, 0.f, 0.f};

    const int aslab = g2;
    const int bbase = 2 + 3 * g2;

    for (int k0 = 0; k0 < KDIM; k0 += BK) {
        // ---- stage this wave's slab: 8 x 1KB direct global->LDS ----
        #pragma unroll
        for (int i = 0; i < 8; ++i) {
            const int row = i * 8 + rsub;
            const unsigned short* g = gbase + (size_t)row * grstr + k0 + lch * 8;
            void* l = (void*)((char*)&smem.bf[wave][i * 512] + lane * 16);
            async16(g, l);
        }
        __syncthreads();

        // ---- fragments + MFMA (XOR-unswizzle on read; conflict-free) ----
        short8 afr[2][2];  // [mt][ks]
        #pragma unroll
        for (int mt = 0; mt < 2; ++mt)
            #pragma unroll
            for (int ks = 0; ks < 2; ++ks) {
                const int row = wm * 32 + mt * 16 + lr;
                const int ch  = (ks * 4 + q) ^ (lr & 7);
                afr[mt][ks] = *(const short8*)&smem.bf[aslab][row * 64 + ch * 8];
            }
        #pragma unroll
        for (int g = 0; g < 3; ++g)
            #pragma unroll
            for (int nt = 0; nt < 2; ++nt)
                #pragma unroll
                for (int ks = 0; ks < 2; ++ks) {
                    const int row = wn * 32 + nt * 16 + lr;
                    const int ch  = (ks * 4 + q) ^ (lr & 7);
                    const short8 bfr = *(const short8*)&smem.bf[bbase + g][row * 64 + ch * 8];
                    #pragma unroll
                    for (int mt = 0; mt < 2; ++mt)
                        acc[g][mt][nt] = __builtin_amdgcn_mfma_f32_16x16x32_bf16(
                            afr[mt][ks], bfr, acc[g][mt][nt], 0, 0, 0);
                }
        __syncthreads();
    }

    // ---- epilogue: gh waves publish to LDS, gx waves combine + store ----
    const float* bih = b_ih + u * (3 * H_);
    const float* bhh = b_hh + u * (3 * H_);

    if (g2 == 1) {
        #pragma unroll
        for (int nt = 0; nt < 2; ++nt) {
            const int col = wn * 32 + nt * 16 + lr;
            const float bhr = bhh[h0 + col];
            const float bhz = bhh[H_ + h0 + col];
            const float bhn = bhh[2 * H_ + h0 + col];
            #pragma unroll
            for (int mt = 0; mt < 2; ++mt)
                #pragma unroll
                for (int r = 0; r < 4; ++r) {
                    const int row = wm * 32 + mt * 16 + q * 4 + r;
                    smem.ep[0][row * ESTR + col] = acc[0][mt][nt][r] + bhr;
                    smem.ep[1][row * ESTR + col] = acc[1][mt][nt][r] + bhz;
                    smem.ep[2][row * ESTR + col] = acc[2][mt][nt][r] + bhn;
                }
        }
    }
    __syncthreads();

    if (g2 == 0) {
        #pragma unroll
        for (int nt = 0; nt < 2; ++nt) {
            const int col  = wn * 32 + nt * 16 + lr;
            const int hcol = h0 + col;
            const float bir  = bih[hcol];
            const float biz  = bih[H_ + hcol];
            const float bin_ = bih[2 * H_ + hcol];
            #pragma unroll
            for (int mt = 0; mt < 2; ++mt)
                #pragma unroll
                for (int r = 0; r < 4; ++r) {
                    const int row  = wm * 32 + mt * 16 + q * 4 + r;
                    const size_t gidx = ((size_t)(b0 + row) * U_ + u) * H_ + hcol;
                    const float hprev = hidden[gidx];
                    const float hr = smem.ep[0][row * ESTR + col];
                    const float hz = smem.ep[1][row * ESTR + col];
                    const float hn = smem.ep[2][row * ESTR + col];
                    const float xr = acc[0][mt][nt][r] + bir;
                    const float xz = acc[1][mt][nt][r] + biz;
                    const float xn = acc[2][mt][nt][r] + bin_;
                    const float rg = 1.f / (1.f + __expf(-(xr + hr)));
                    const float zg = 1.f / (1.f + __expf(-(xz + hz)));
                    const float ng = tanhf(xn + rg * hn);
                    out[gidx] = (1.f - zg) * ng + zg * hprev;
                }
        }
    }
}

// ---------------- Fallback (R3, passed): used only if ws too small ----------------
#define LSTR 40
union SmemF {
    short bf[8][BM * LSTR];
    float ep[3][BM * ESTR];
};

__global__ __launch_bounds__(512, 4)
void gru_fallback_kernel(const float* __restrict__ inputs, const float* __restrict__ hidden,
                         const float* __restrict__ W_ih, const float* __restrict__ W_hh,
                         const float* __restrict__ b_ih, const float* __restrict__ b_hh,
                         float* __restrict__ out)
{
    const int nb = blockIdx.x;
    const int mb = blockIdx.y;
    const int u  = blockIdx.z;
    const int b0 = mb * BM, h0 = nb * BN;
    const int tid = threadIdx.x, lane = tid & 63, wave = tid >> 6;
    const int lr = lane & 15, q = lane >> 4;
    const int wm = wave & 1, wn = (wave >> 1) & 1, g2 = wave >> 2;

    __shared__ SmemF smem;

    const float* srcs[8]; int rstr[8];
    srcs[0] = inputs + ((size_t)b0 * U_ + u) * I_;         rstr[0] = U_ * I_;
    srcs[1] = hidden + ((size_t)b0 * U_ + u) * H_;         rstr[1] = U_ * H_;
    srcs[2] = W_ih + ((size_t)(u * 3 + 0) * H_ + h0) * I_; rstr[2] = I_;
    srcs[3] = W_ih + ((size_t)(u * 3 + 1) * H_ + h0) * I_; rstr[3] = I_;
    srcs[4] = W_ih + ((size_t)(u * 3 + 2) * H_ + h0) * I_; rstr[4] = I_;
    srcs[5] = W_hh + ((size_t)(u * 3 + 0) * H_ + h0) * H_; rstr[5] = H_;
    srcs[6] = W_hh + ((size_t)(u * 3 + 1) * H_ + h0) * H_; rstr[6] = H_;
    srcs[7] = W_hh + ((size_t)(u * 3 + 2) * H_ + h0) * H_; rstr[7] = H_;

    const int srow = tid >> 3, c4 = (tid & 7) * 4;
    const float* tb[8];
    #pragma unroll
    for (int s = 0; s < 8; ++s) tb[s] = srcs[s] + (size_t)srow * rstr[s] + c4;

    floatx4 acc[3][2][2];
    #pragma unroll
    for (int g = 0; g < 3; ++g)
        #pragma unroll
        for (int mt = 0; mt < 2; ++mt)
            #pragma unroll
            for (int nt = 0; nt < 2; ++nt) acc[g][mt][nt] = (floatx4){0.f, 0.f, 0.f, 0.f};

    const int aslab = g2, bbase = 2 + 3 * g2;
    float4 pre[8];
    #pragma unroll
    for (int s = 0; s < 8; ++s) pre[s] = *(const float4*)(tb[s]);

    for (int k0 = 0; k0 < KDIM; k0 += 32) {
        #pragma unroll
        for (int s = 0; s < 8; ++s) {
            uint2 w; w.x = pk2bf(pre[s].x, pre[s].y); w.y = pk2bf(pre[s].z, pre[s].w);
            *(uint2*)&smem.bf[s][srow * LSTR + c4] = w;
        }
        __syncthreads();
        if (k0 + 32 < KDIM) {
            #pragma unroll
            for (int s = 0; s < 8; ++s) pre[s] = *(const float4*)(tb[s] + k0 + 32);
        }
        short8 afr[2];
        #pragma unroll
        for (int mt = 0; mt < 2; ++mt)
            afr[mt] = *(const short8*)&smem.bf[aslab][(wm * 32 + mt * 16 + lr) * LSTR + q * 8];
        #pragma unroll
        for (int g = 0; g < 3; ++g) {
            const short8 bf0 = *(const short8*)&smem.bf[bbase + g][(wn * 32 + lr) * LSTR + q * 8];
            const short8 bf1 = *(const short8*)&smem.bf[bbase + g][(wn * 32 + 16 + lr) * LSTR + q * 8];
            #pragma unroll
            for (int mt = 0; mt < 2; ++mt) {
                acc[g][mt][0] = __builtin_amdgcn_mfma_f32_16x16x32_bf16(afr[mt], bf0, acc[g][mt][0], 0, 0, 0);
                acc[g][mt][1] = __builtin_amdgcn_mfma_f32_16x16x32_bf16(afr[mt], bf1, acc[g][mt][1], 0, 0, 0);
            }
        }
        __syncthreads();
    }

    const float* bih = b_ih + u * (3 * H_);
    const float* bhh = b_hh + u * (3 * H_);
    if (g2 == 1) {
        #pragma unroll
        for (int nt = 0; nt < 2; ++nt) {
            const int col = wn * 32 + nt * 16 + lr;
            const float bhr = bhh[h0 + col], bhz = bhh[H_ + h0 + col], bhn = bhh[2 * H_ + h0 + col];
            #pragma unroll
            for (int mt = 0; mt < 2; ++mt)
                #pragma unroll
                for (int r = 0; r < 4; ++r) {
                    const int row = wm * 32 + mt * 16 + q * 4 + r;
                    smem.ep[0][row * ESTR + col] = acc[0][mt][nt][r] + bhr;
                    smem.ep[1][row * ESTR + col] = acc[1][mt][nt][r] + bhz;
                    smem.ep[2][row * ESTR + col] = acc[2][mt][nt][r] + bhn;
                }
        }
    }
    __syncthreads();
    if (g2 == 0) {
        #pragma unroll
        for (int nt = 0; nt < 2; ++nt) {
            const int col = wn * 32 + nt * 16 + lr, hcol = h0 + col;
            const float bir = bih[hcol], biz = bih[H_ + hcol], bin_ = bih[2 * H_ + hcol];
            #pragma unroll
            for (int mt = 0; mt < 2; ++mt)
                #pragma unroll
                for (int r = 0; r < 4; ++r) {
                    const int row = wm * 32 + mt * 16 + q * 4 + r;
                    const size_t gidx = ((size_t)(b0 + row) * U_ + u) * H_ + hcol;
                    const float hprev = hidden[gidx];
                    const float hr = smem.ep[0][row * ESTR + col];
                    const float hz = smem.ep[1][row * ESTR + col];
                    const float hn = smem.ep[2][row * ESTR + col];
                    const float xr = acc[0][mt][nt][r] + bir;
                    const float xz = acc[1][mt][nt][r] + biz;
                    const float xn = acc[2][mt][nt][r] + bin_;
                    const float rg = 1.f / (1.f + __expf(-(xr + hr)));
                    const float zg = 1.f / (1.f + __expf(-(xz + hz)));
                    const float ng = tanhf(xn + rg * hn);
                    out[gidx] = (1.f - zg) * ng + zg * hprev;
                }
        }
    }
}

extern "C" void kernel_launch(void* const* d_in, const int* in_sizes, int n_in,
                              void* d_out, int out_size, void* d_ws, size_t ws_size,
                              hipStream_t stream) {
    const float* inputs = (const float*)d_in[0];
    const float* hidden = (const float*)d_in[1];
    const float* W_ih   = (const float*)d_in[2];
    const float* W_hh   = (const float*)d_in[3];
    const float* b_ih   = (const float*)d_in[4];
    const float* b_hh   = (const float*)d_in[5];
    float* out = (float*)d_out;

    if (ws_size >= WS_NEED) {
        unsigned short* ws = (unsigned short*)d_ws;
        convert_bf16_kernel<<<NTOT / 2048, 256, 0, stream>>>(inputs, hidden, W_ih, W_hh, ws);
        dim3 grid(64, 16, 1);  // x = u*8+nb (id%8 = nb -> XCD-local weights), y = mb
        gru_main_kernel<<<grid, 512, 0, stream>>>(ws, hidden, b_ih, b_hh, out);
    } else {
        dim3 grid(8, 16, 8);
        gru_fallback_kernel<<<grid, 512, 0, stream>>>(inputs, hidden, W_ih, W_hh, b_ih, b_hh, out);
    }
}

// Round 5
// 175.378 us; speedup vs baseline: 1.1466x; 1.1466x over previous
//
#include <hip/hip_runtime.h>
#include <hip/hip_bf16.h>
#include <stdint.h>

// GroupTorchGRU: B=1024, U=8, I=H=512, fp32 in/out.
// R5: two-kernel design.
//  K1: fp32 -> bf16 prepass into d_ws (42 MB).
//  K2: fused GEMM+gates, double-buffered global_load_lds pipeline (BK=32,
//      2x32KB buffers): loads for buf[n+1] issued before MFMA on buf[n], so
//      the vmcnt(0) barrier drain is covered by the compute phase.
//      128B-line XOR swizzle: staging writes lane-contiguous (global_load_lds
//      requirement) AND ds_read_b128 fragment reads 2-way/phase = conflict-free.
//      Gate-split waves (4 gx, 4 gh), XCD-aware grid (id%8 = h-tile).
// Fallback: R3 single-kernel path if ws too small.

#define B_ 1024
#define U_ 8
#define I_ 512
#define H_ 512
#define KDIM 512

#define NX (B_ * U_ * I_)
#define NW (U_ * 3 * H_ * I_)
#define OFF_X 0
#define OFF_H NX
#define OFF_WIH (2 * NX)
#define OFF_WHH (2 * NX + NW)
#define NTOT (2 * NX + 2 * NW)
#define WS_NEED ((size_t)NTOT * 2)

#define BM 64
#define BN 64
#define BK 32
#define NITER (KDIM / BK)        // 16
#define SLAB_B 4096              // 64 rows x 64B (32 bf16)
#define BUF_B (8 * SLAB_B)       // 32KB per buffer
#define ESTR 68                  // fp32 epilogue row stride (64+4)

typedef __attribute__((ext_vector_type(8))) short short8;
typedef __attribute__((ext_vector_type(4))) float floatx4;

__device__ __forceinline__ unsigned int pk2bf(float a, float b) {
    float2 f2; f2.x = a; f2.y = b;
    union { __hip_bfloat162 h; unsigned int u; } cv;
    cv.h = __float22bfloat162_rn(f2);
    return cv.u;
}

__device__ __forceinline__ void async16(const void* g, void* l) {
    __builtin_amdgcn_global_load_lds(
        (const __attribute__((address_space(1))) void*)g,
        (__attribute__((address_space(3))) void*)l, 16, 0, 0);
}

// ---------------- K1: fp32 -> bf16 prepass ----------------
__global__ __launch_bounds__(256)
void convert_bf16_kernel(const float* __restrict__ x, const float* __restrict__ h,
                         const float* __restrict__ wih, const float* __restrict__ whh,
                         unsigned short* __restrict__ ws)
{
    const size_t base = ((size_t)blockIdx.x * 256 + threadIdx.x) * 8;
    const float* src; size_t off;
    if (base < (size_t)OFF_H)        { src = x;   off = OFF_X; }
    else if (base < (size_t)OFF_WIH) { src = h;   off = OFF_H; }
    else if (base < (size_t)OFF_WHH) { src = wih; off = OFF_WIH; }
    else                             { src = whh; off = OFF_WHH; }
    const float4 v0 = *(const float4*)(src + (base - off));
    const float4 v1 = *(const float4*)(src + (base - off) + 4);
    uint4 o;
    o.x = pk2bf(v0.x, v0.y);
    o.y = pk2bf(v0.z, v0.w);
    o.z = pk2bf(v1.x, v1.y);
    o.w = pk2bf(v1.z, v1.w);
    *(uint4*)(ws + base) = o;
}

// ---------------- K2: fused bf16 GEMM + GRU gates ----------------
// Slab layout (64 rows x 32 bf16): 128B "lines" = 2 rows; 8 x 16B positions
// per line. Physical position p of line L holds logical position p ^ (L&7),
// where logical position = (row&1)*4 + kchunk.
union Smem {
    char raw[2 * BUF_B];             // 64KB: 2 buffers x 8 slabs x 4KB
    float ep[3][BM * ESTR];          // 52224B epilogue exchange
};

__global__ __launch_bounds__(512, 4)
void gru_main_kernel(const unsigned short* __restrict__ ws,
                     const float* __restrict__ hidden,
                     const float* __restrict__ b_ih,
                     const float* __restrict__ b_hh,
                     float* __restrict__ out)
{
    const int u  = blockIdx.x >> 3;  // id%8 = nb -> XCD-local weight set (3MB/XCD)
    const int nb = blockIdx.x & 7;
    const int mb = blockIdx.y;
    const int b0 = mb * BM;
    const int h0 = nb * BN;

    const int tid  = threadIdx.x;
    const int lane = tid & 63;
    const int wave = tid >> 6;        // 0..7, also = slab this wave stages
    const int lr   = lane & 15;
    const int q    = lane >> 4;
    const int wm   = wave & 1;
    const int wn   = (wave >> 1) & 1;
    const int g2   = wave >> 2;       // 0: gx waves, 1: gh waves

    __shared__ Smem smem;

    // slabs: 0=X, 1=Hprev, 2..4=W_ih r/z/n, 5..7=W_hh r/z/n
    const unsigned short* gbase; int grstr;
    if (wave == 0)      { gbase = ws + OFF_X + ((size_t)b0 * U_ + u) * I_; grstr = U_ * I_; }
    else if (wave == 1) { gbase = ws + OFF_H + ((size_t)b0 * U_ + u) * H_; grstr = U_ * H_; }
    else if (wave <= 4) { int g = wave - 2; gbase = ws + OFF_WIH + ((size_t)(u * 3 + g) * H_ + h0) * I_; grstr = I_; }
    else                { int g = wave - 5; gbase = ws + OFF_WHH + ((size_t)(u * 3 + g) * H_ + h0) * H_; grstr = H_; }

    // ---- staging addresses (4 x 1KB instrs per wave per iter) ----
    // instr i: lines i*8 .. i*8+7; lane -> line = i*8 + lane>>3, phys pos = lane&7
    const unsigned short* gptr[4];
    int ldsoff[4];
    #pragma unroll
    for (int i = 0; i < 4; ++i) {
        const int line = i * 8 + (lane >> 3);
        const int pos  = (lane & 7) ^ (line & 7);   // logical position
        const int row  = 2 * line + (pos >> 2);
        const int ch   = pos & 3;
        gptr[i]   = gbase + (size_t)row * grstr + ch * 8;
        ldsoff[i] = wave * SLAB_B + i * 1024 + lane * 16;
    }

    // ---- fragment read offsets (slab-relative bytes) ----
    // logical (r, kchunk=q): line = r>>1, pos = (r&1)*4+q, phys = pos^(line&7)
    int aoff[2], boff[2];
    #pragma unroll
    for (int t = 0; t < 2; ++t) {
        {   // A: r = wm*32 + t*16 + lr
            const int r = wm * 32 + t * 16 + lr;
            const int line = r >> 1;
            const int pp = (((r & 1) * 4 + q)) ^ (line & 7);
            aoff[t] = line * 128 + pp * 16;
        }
        {   // B: r = wn*32 + t*16 + lr
            const int r = wn * 32 + t * 16 + lr;
            const int line = r >> 1;
            const int pp = (((r & 1) * 4 + q)) ^ (line & 7);
            boff[t] = line * 128 + pp * 16;
        }
    }

    floatx4 acc[3][2][2];
    #pragma unroll
    for (int g = 0; g < 3; ++g)
        #pragma unroll
        for (int mt = 0; mt < 2; ++mt)
            #pragma unroll
            for (int nt = 0; nt < 2; ++nt)
                acc[g][mt][nt] = (floatx4){0.f, 0.f, 0.f, 0.f};

    const int aslab = g2;
    const int bbase = 2 + 3 * g2;

    // ---- prologue: loads for buffer 0 ----
    #pragma unroll
    for (int i = 0; i < 4; ++i) {
        async16(gptr[i], smem.raw + ldsoff[i]);
        gptr[i] += BK;
    }

    for (int it = 0; it < NITER; ++it) {
        const int cur = it & 1;
        __syncthreads();   // drains buf[cur] loads (in flight through prev MFMA phase)

        if (it + 1 < NITER) {
            const int nxtoff = ((it + 1) & 1) * BUF_B;
            #pragma unroll
            for (int i = 0; i < 4; ++i) {
                async16(gptr[i], smem.raw + nxtoff + ldsoff[i]);
                gptr[i] += BK;
            }
        }

        const char* base = smem.raw + cur * BUF_B;
        const short8 a0 = *(const short8*)(base + aslab * SLAB_B + aoff[0]);
        const short8 a1 = *(const short8*)(base + aslab * SLAB_B + aoff[1]);
        #pragma unroll
        for (int g = 0; g < 3; ++g) {
            const char* bslab = base + (bbase + g) * SLAB_B;
            #pragma unroll
            for (int nt = 0; nt < 2; ++nt) {
                const short8 bf = *(const short8*)(bslab + boff[nt]);
                acc[g][0][nt] = __builtin_amdgcn_mfma_f32_16x16x32_bf16(a0, bf, acc[g][0][nt], 0, 0, 0);
                acc[g][1][nt] = __builtin_amdgcn_mfma_f32_16x16x32_bf16(a1, bf, acc[g][1][nt], 0, 0, 0);
            }
        }
    }
    __syncthreads();   // all fragment reads done before ep overwrites buffers

    // ---- epilogue: gh waves publish to LDS, gx waves combine + store ----
    const float* bih = b_ih + u * (3 * H_);
    const float* bhh = b_hh + u * (3 * H_);

    if (g2 == 1) {
        #pragma unroll
        for (int nt = 0; nt < 2; ++nt) {
            const int col = wn * 32 + nt * 16 + lr;
            const float bhr = bhh[h0 + col];
            const float bhz = bhh[H_ + h0 + col];
            const float bhn = bhh[2 * H_ + h0 + col];
            #pragma unroll
            for (int mt = 0; mt < 2; ++mt)
                #pragma unroll
                for (int r = 0; r < 4; ++r) {
                    const int row = wm * 32 + mt * 16 + q * 4 + r;
                    smem.ep[0][row * ESTR + col] = acc[0][mt][nt][r] + bhr;
                    smem.ep[1][row * ESTR + col] = acc[1][mt][nt][r] + bhz;
                    smem.ep[2][row * ESTR + col] = acc[2][mt][nt][r] + bhn;
                }
        }
    }
    __syncthreads();

    if (g2 == 0) {
        #pragma unroll
        for (int nt = 0; nt < 2; ++nt) {
            const int col  = wn * 32 + nt * 16 + lr;
            const int hcol = h0 + col;
            const float bir  = bih[hcol];
            const float biz  = bih[H_ + hcol];
            const float bin_ = bih[2 * H_ + hcol];
            #pragma unroll
            for (int mt = 0; mt < 2; ++mt)
                #pragma unroll
                for (int r = 0; r < 4; ++r) {
                    const int row  = wm * 32 + mt * 16 + q * 4 + r;
                    const size_t gidx = ((size_t)(b0 + row) * U_ + u) * H_ + hcol;
                    const float hprev = hidden[gidx];
                    const float hr = smem.ep[0][row * ESTR + col];
                    const float hz = smem.ep[1][row * ESTR + col];
                    const float hn = smem.ep[2][row * ESTR + col];
                    const float xr = acc[0][mt][nt][r] + bir;
                    const float xz = acc[1][mt][nt][r] + biz;
                    const float xn = acc[2][mt][nt][r] + bin_;
                    const float rg = 1.f / (1.f + __expf(-(xr + hr)));
                    const float zg = 1.f / (1.f + __expf(-(xz + hz)));
                    const float ng = tanhf(xn + rg * hn);
                    out[gidx] = (1.f - zg) * ng + zg * hprev;
                }
        }
    }
}

// ---------------- Fallback (R3, passed): used only if ws too small ----------------
#define LSTR 40
union SmemF {
    short bf[8][BM * LSTR];
    float ep[3][BM * ESTR];
};

__global__ __launch_bounds__(512, 4)
void gru_fallback_kernel(const float* __restrict__ inputs, const float* __restrict__ hidden,
                         const float* __restrict__ W_ih, const float* __restrict__ W_hh,
                         const float* __restrict__ b_ih, const float* __restrict__ b_hh,
                         float* __restrict__ out)
{
    const int nb = blockIdx.x;
    const int mb = blockIdx.y;
    const int u  = blockIdx.z;
    const int b0 = mb * BM, h0 = nb * BN;
    const int tid = threadIdx.x, lane = tid & 63, wave = tid >> 6;
    const int lr = lane & 15, q = lane >> 4;
    const int wm = wave & 1, wn = (wave >> 1) & 1, g2 = wave >> 2;

    __shared__ SmemF smem;

    const float* srcs[8]; int rstr[8];
    srcs[0] = inputs + ((size_t)b0 * U_ + u) * I_;         rstr[0] = U_ * I_;
    srcs[1] = hidden + ((size_t)b0 * U_ + u) * H_;         rstr[1] = U_ * H_;
    srcs[2] = W_ih + ((size_t)(u * 3 + 0) * H_ + h0) * I_; rstr[2] = I_;
    srcs[3] = W_ih + ((size_t)(u * 3 + 1) * H_ + h0) * I_; rstr[3] = I_;
    srcs[4] = W_ih + ((size_t)(u * 3 + 2) * H_ + h0) * I_; rstr[4] = I_;
    srcs[5] = W_hh + ((size_t)(u * 3 + 0) * H_ + h0) * H_; rstr[5] = H_;
    srcs[6] = W_hh + ((size_t)(u * 3 + 1) * H_ + h0) * H_; rstr[6] = H_;
    srcs[7] = W_hh + ((size_t)(u * 3 + 2) * H_ + h0) * H_; rstr[7] = H_;

    const int srow = tid >> 3, c4 = (tid & 7) * 4;
    const float* tb[8];
    #pragma unroll
    for (int s = 0; s < 8; ++s) tb[s] = srcs[s] + (size_t)srow * rstr[s] + c4;

    floatx4 acc[3][2][2];
    #pragma unroll
    for (int g = 0; g < 3; ++g)
        #pragma unroll
        for (int mt = 0; mt < 2; ++mt)
            #pragma unroll
            for (int nt = 0; nt < 2; ++nt) acc[g][mt][nt] = (floatx4){0.f, 0.f, 0.f, 0.f};

    const int aslab = g2, bbase = 2 + 3 * g2;
    float4 pre[8];
    #pragma unroll
    for (int s = 0; s < 8; ++s) pre[s] = *(const float4*)(tb[s]);

    for (int k0 = 0; k0 < KDIM; k0 += 32) {
        #pragma unroll
        for (int s = 0; s < 8; ++s) {
            uint2 w; w.x = pk2bf(pre[s].x, pre[s].y); w.y = pk2bf(pre[s].z, pre[s].w);
            *(uint2*)&smem.bf[s][srow * LSTR + c4] = w;
        }
        __syncthreads();
        if (k0 + 32 < KDIM) {
            #pragma unroll
            for (int s = 0; s < 8; ++s) pre[s] = *(const float4*)(tb[s] + k0 + 32);
        }
        short8 afr[2];
        #pragma unroll
        for (int mt = 0; mt < 2; ++mt)
            afr[mt] = *(const short8*)&smem.bf[aslab][(wm * 32 + mt * 16 + lr) * LSTR + q * 8];
        #pragma unroll
        for (int g = 0; g < 3; ++g) {
            const short8 bf0 = *(const short8*)&smem.bf[bbase + g][(wn * 32 + lr) * LSTR + q * 8];
            const short8 bf1 = *(const short8*)&smem.bf[bbase + g][(wn * 32 + 16 + lr) * LSTR + q * 8];
            #pragma unroll
            for (int mt = 0; mt < 2; ++mt) {
                acc[g][mt][0] = __builtin_amdgcn_mfma_f32_16x16x32_bf16(afr[mt], bf0, acc[g][mt][0], 0, 0, 0);
                acc[g][mt][1] = __builtin_amdgcn_mfma_f32_16x16x32_bf16(afr[mt], bf1, acc[g][mt][1], 0, 0, 0);
            }
        }
        __syncthreads();
    }

    const float* bih = b_ih + u * (3 * H_);
    const float* bhh = b_hh + u * (3 * H_);
    if (g2 == 1) {
        #pragma unroll
        for (int nt = 0; nt < 2; ++nt) {
            const int col = wn * 32 + nt * 16 + lr;
            const float bhr = bhh[h0 + col], bhz = bhh[H_ + h0 + col], bhn = bhh[2 * H_ + h0 + col];
            #pragma unroll
            for (int mt = 0; mt < 2; ++mt)
                #pragma unroll
                for (int r = 0; r < 4; ++r) {
                    const int row = wm * 32 + mt * 16 + q * 4 + r;
                    smem.ep[0][row * ESTR + col] = acc[0][mt][nt][r] + bhr;
                    smem.ep[1][row * ESTR + col] = acc[1][mt][nt][r] + bhz;
                    smem.ep[2][row * ESTR + col] = acc[2][mt][nt][r] + bhn;
                }
        }
    }
    __syncthreads();
    if (g2 == 0) {
        #pragma unroll
        for (int nt = 0; nt < 2; ++nt) {
            const int col = wn * 32 + nt * 16 + lr, hcol = h0 + col;
            const float bir = bih[hcol], biz = bih[H_ + hcol], bin_ = bih[2 * H_ + hcol];
            #pragma unroll
            for (int mt = 0; mt < 2; ++mt)
                #pragma unroll
                for (int r = 0; r < 4; ++r) {
                    const int row = wm * 32 + mt * 16 + q * 4 + r;
                    const size_t gidx = ((size_t)(b0 + row) * U_ + u) * H_ + hcol;
                    const float hprev = hidden[gidx];
                    const float hr = smem.ep[0][row * ESTR + col];
                    const float hz = smem.ep[1][row * ESTR + col];
                    const float hn = smem.ep[2][row * ESTR + col];
                    const float xr = acc[0][mt][nt][r] + bir;
                    const float xz = acc[1][mt][nt][r] + biz;
                    const float xn = acc[2][mt][nt][r] + bin_;
                    const float rg = 1.f / (1.f + __expf(-(xr + hr)));
                    const float zg = 1.f / (1.f + __expf(-(xz + hz)));
                    const float ng = tanhf(xn + rg * hn);
                    out[gidx] = (1.f - zg) * ng + zg * hprev;
                }
        }
    }
}

extern "C" void kernel_launch(void* const* d_in, const int* in_sizes, int n_in,
                              void* d_out, int out_size, void* d_ws, size_t ws_size,
                              hipStream_t stream) {
    const float* inputs = (const float*)d_in[0];
    const float* hidden = (const float*)d_in[1];
    const float* W_ih   = (const float*)d_in[2];
    const float* W_hh   = (const float*)d_in[3];
    const float* b_ih   = (const float*)d_in[4];
    const float* b_hh   = (const float*)d_in[5];
    float* out = (float*)d_out;

    if (ws_size >= WS_NEED) {
        unsigned short* ws = (unsigned short*)d_ws;
        convert_bf16_kernel<<<NTOT / 2048, 256, 0, stream>>>(inputs, hidden, W_ih, W_hh, ws);
        dim3 grid(64, 16, 1);  // x = u*8+nb, y = mb
        gru_main_kernel<<<grid, 512, 0, stream>>>(ws, hidden, b_ih, b_hh, out);
    } else {
        dim3 grid(8, 16, 8);
        gru_fallback_kernel<<<grid, 512, 0, stream>>>(inputs, hidden, W_ih, W_hh, b_ih, b_hh, out);
    }
}